// Round 7
// baseline (537.491 us; speedup 1.0000x reference)
//
#include <hip/hip_runtime.h>
#include <hip/hip_bf16.h>

// ============================================================================
// HybridModel round 7: l3 zo-merge (one block = all 64 oc) + LDS bank-conflict
// pads (l3 position stride 32->36 f16; l2 16->20 f16). l1/head unchanged.
// ============================================================================

typedef _Float16 f16;
typedef _Float16 f16x2 __attribute__((ext_vector_type(2)));
typedef _Float16 f16x4 __attribute__((ext_vector_type(4)));
typedef _Float16 f16x8 __attribute__((ext_vector_type(8)));
typedef float f32x4 __attribute__((ext_vector_type(4)));
typedef float f32x16 __attribute__((ext_vector_type(16)));

#define DEV static __device__ __forceinline__

DEV float wave_sum(float v) {
#pragma unroll
  for (int off = 32; off > 0; off >>= 1) v += __shfl_xor(v, off, 64);
  return v;
}

// ---------------------------------------------------------------------------
// Weight repack: Bt2[32][168] (k = tap*16+ic, pad 144..167 = 0),
//                Bt3[64][296] (k = tap*32+ic, pad 288..295 = 0), f16.
// ---------------------------------------------------------------------------
__global__ __launch_bounds__(256) void repack(const float* __restrict__ w2,
                                              const float* __restrict__ w3,
                                              f16* __restrict__ Bt2,
                                              f16* __restrict__ Bt3) {
  int t = blockIdx.x * 256 + threadIdx.x;
  int T = gridDim.x * 256;
  for (int i = t; i < 32 * 168; i += T) {
    int oc = i / 168, kk = i - oc * 168;
    float v = 0.f;
    if (kk < 144) {
      int tap = kk >> 4, ic = kk & 15;
      v = w2[(oc * 16 + ic) * 9 + tap];
    }
    Bt2[i] = (f16)v;
  }
  for (int i = t; i < 64 * 296; i += T) {
    int oc = i / 296, kk = i - oc * 296;
    float v = 0.f;
    if (kk < 288) {
      int tap = kk / 32, ic = kk & 31;
      v = w3[(oc * 32 + ic) * 9 + tap];
    }
    Bt3[i] = (f16)v;
  }
}

// ---------------------------------------------------------------------------
// Finalize: banks[64][2][C] -> scsh[2][C]  (scale, shift). 64 thr = 1 wave.
// ---------------------------------------------------------------------------
__global__ __launch_bounds__(64) void finalize(const float* __restrict__ banks,
                                               const float* __restrict__ g,
                                               const float* __restrict__ b,
                                               float* __restrict__ scsh, int C,
                                               float inv_n) {
  int c = blockIdx.x, bk = threadIdx.x;
  float s = banks[bk * 2 * C + c];
  float qq = banks[bk * 2 * C + C + c];
  s = wave_sum(s);
  qq = wave_sum(qq);
  if (bk == 0) {
    float mean = s * inv_n;
    float var = qq * inv_n - mean * mean;
    float sc = g[c] * rsqrtf(var + 1e-5f);
    scsh[c] = sc;
    scsh[C + c] = b[c] - mean * sc;
  }
}

// ---------------------------------------------------------------------------
// L1 via 32x32x16 MFMA (dual-output-row). Unchanged from round 6.
// ---------------------------------------------------------------------------
__global__ __launch_bounds__(256) void l1_mfma32(const float* __restrict__ x,
                                                 const float* __restrict__ w1,
                                                 float* __restrict__ banks,
                                                 f16* __restrict__ h1raw) {
  __shared__ f16 xA[18 * 240];
  __shared__ f16 xB[18 * 240];
  __shared__ f16 lrow[4 * 3616];  // per wave: [2 s][1808]
  __shared__ float lstat[32];
  int bid = blockIdx.x;
  int n = bid / 14, band = bid - n * 14;
  int y0 = band * 16;
  int t = threadIdx.x;
  if (t < 32) lstat[t] = 0.f;
  for (int i = t; i < 1008; i += 256) {
    int r = i / 56, k = i - r * 56;
    int y = y0 - 1 + r;
    float4 v = make_float4(0.f, 0.f, 0.f, 0.f);
    if ((unsigned)y < 224u)
      v = *(const float4*)(x + ((size_t)(n * 224 + y)) * 224 + k * 4);
    f16 h0 = (f16)v.x, h1 = (f16)v.y, h2 = (f16)v.z, h3 = (f16)v.w;
    f16* pa = xA + r * 240 + 4 * k + 1;
    pa[0] = h0; pa[1] = h1; pa[2] = h2; pa[3] = h3;
    f16x4 pk = {h0, h1, h2, h3};
    *(f16x4*)(xB + r * 240 + 4 * k) = pk;
  }
  if (t < 18) {
    xA[t * 240 + 0] = (f16)0.f;
    xA[t * 240 + 225] = (f16)0.f;
    xA[t * 240 + 226] = (f16)0.f;
    xB[t * 240 + 224] = (f16)0.f;
    xB[t * 240 + 225] = (f16)0.f;
  }
  __syncthreads();

  int wave = t >> 6, lane = t & 63;
  int g = lane >> 5, m32 = lane & 31;
  int oc = m32 & 15, s = m32 >> 4;

  f16x8 b;
#pragma unroll
  for (int j = 0; j < 8; j++) {
    int ky = 2 * g + (j >> 2), kx = j & 3;
    int kys = ky - s;
    float wv = 0.f;
    if (kx < 3 && kys >= 0 && kys < 3) wv = w1[oc * 9 + kys * 3 + kx];
    b[j] = (f16)wv;
  }

  const f16* abase = (m32 & 1) ? (xB + (m32 - 1)) : (xA + m32);
  f16* myrow = lrow + wave * 3616;
  f16* mrow = myrow + s * 1808;
  f32x16 zero16;
#pragma unroll
  for (int r = 0; r < 16; r++) zero16[r] = 0.f;
  const int bp[8] = {0, 1, 4, 5, 8, 9, 12, 13};
  float ssum = 0.f, ssq = 0.f;

  for (int rp = wave; rp < 8; rp += 4) {
    int r0 = 2 * rp + 2 * g;
    const f16* rbase = abase + r0 * 240;
#pragma unroll
    for (int xt = 0; xt < 7; xt++) {
      const f16* p0 = rbase + xt * 32;
      f16x2 v0 = *(const f16x2*)(p0);
      f16x2 v1 = *(const f16x2*)(p0 + 2);
      f16x2 v2 = *(const f16x2*)(p0 + 240);
      f16x2 v3 = *(const f16x2*)(p0 + 242);
      f16x8 a = {v0[0], v0[1], v1[0], v1[1], v2[0], v2[1], v3[0], v3[1]};
      f32x16 acc = __builtin_amdgcn_mfma_f32_32x32x16_f16(a, b, zero16, 0, 0, 0);
#pragma unroll
      for (int r = 0; r < 16; r++) {
        float v = acc[r];
        ssum += v;
        ssq += v * v;
      }
#pragma unroll
      for (int i = 0; i < 8; i++) {
        float pm = fmaxf(acc[2 * i], acc[2 * i + 1]);
        int pxp = xt * 16 + bp[i] + 2 * g;
        mrow[pxp * 16 + oc] = (f16)pm;
      }
    }
    int ph = band * 8 + rp;
    f16* gdst = h1raw + ((size_t)(n * 112) + ph) * 112 * 16;
    for (int i = lane; i < 224; i += 64) {
      f16x8 va = *(const f16x8*)(myrow + i * 8);
      f16x8 vb = *(const f16x8*)(myrow + 1808 + i * 8);
#pragma unroll
      for (int k = 0; k < 8; k++) va[k] = (va[k] > vb[k]) ? va[k] : vb[k];
      *(f16x8*)(gdst + i * 8) = va;
    }
  }
  ssum += __shfl_xor(ssum, 16, 64);
  ssum += __shfl_xor(ssum, 32, 64);
  ssq += __shfl_xor(ssq, 16, 64);
  ssq += __shfl_xor(ssq, 32, 64);
  if (lane < 16) {
    atomicAdd(&lstat[oc], ssum);
    atomicAdd(&lstat[16 + oc], ssq);
  }
  __syncthreads();
  if (t < 32) atomicAdd(&banks[(bid & 63) * 32 + t], lstat[t]);
}

// ---------------------------------------------------------------------------
// L2 GEMM: h1raw -> stage BN1+relu -> raw conv2, stats + maxpool -> p2.
// Round 7: lin position stride padded 16 -> 20 f16 (bank-conflict-free).
// ---------------------------------------------------------------------------
__global__ __launch_bounds__(256) void l2_gemm(const f16* __restrict__ h1,
                                               const f16* __restrict__ Btg,
                                               const float* __restrict__ scsh1,
                                               f16* __restrict__ p2,
                                               float* __restrict__ banks) {
  extern __shared__ char smem[];
  f16* lin = (f16*)smem;                    // [6][114] pos x 20 f16 = 27360 B
  f16* lB = (f16*)(smem + 27360);           // [32][168]    = 10752 B
  f16* lpool = (f16*)(smem + 38112);        // [2][56][32]  =  7168 B
  float* lstat = (float*)(smem + 45280);    // [2][32]      =   256 B
  int bid = blockIdx.x;
  int n = bid / 28, band = bid - n * 28, h0 = band * 4;
  int t = threadIdx.x;
  if (t < 64) lstat[t] = 0.f;
  {
    const uint4* s = (const uint4*)Btg;
    uint4* d = (uint4*)lB;
    for (int i = t; i < 672; i += 256) d[i] = s[i];
  }
  {
    for (int i = t; i < 1344; i += 256) {
      int r = i / 224, c = i - r * 224;  // c: f16x8 unit (pos = c>>1, half = c&1)
      int y = h0 + r - 1;
      f16x8 o = {0, 0, 0, 0, 0, 0, 0, 0};
      if ((unsigned)y < 112u) {
        f16x8 xv =
            *(const f16x8*)(h1 + ((size_t)(n * 112 + y)) * 112 * 16 + c * 8);
        int ch0 = (c & 1) * 8;
#pragma unroll
        for (int k = 0; k < 8; k++) {
          float f = (float)xv[k] * scsh1[ch0 + k] + scsh1[16 + ch0 + k];
          o[k] = (f16)fmaxf(f, 0.f);
        }
      }
      *(f16x8*)(lin + (r * 114 + 1 + (c >> 1)) * 20 + (c & 1) * 8) = o;
    }
    if (t < 24) {
      int r = t >> 2, k = t & 3;
      f16x8 z = {0, 0, 0, 0, 0, 0, 0, 0};
      int addr = (k < 2) ? ((r * 114 + 0) * 20 + k * 8)
                         : ((r * 114 + 113) * 20 + (k - 2) * 8);
      *(f16x8*)(lin + addr) = z;
    }
  }
  __syncthreads();
  int wave = t >> 6, lane = t & 63, q = lane >> 4, wi = lane & 15;
  const int icq = (q & 1) * 8;
  f32x4 acc[7][2];
#pragma unroll
  for (int f = 0; f < 7; f++)
#pragma unroll
    for (int nf = 0; nf < 2; nf++)
#pragma unroll
      for (int r = 0; r < 4; r++) acc[f][nf][r] = 0.f;

#pragma unroll
  for (int j = 0; j < 5; j++) {
    const int tA = 2 * j, tB = 2 * j + 1;
    const int kyA = tA / 3, kxA = tA % 3;
    const int kyB = (tB < 9) ? tB / 3 : 0, kxB = (tB < 9) ? tB % 3 : 0;
    bool hiq = (q >= 2);
    int ky = hiq ? kyB : kyA;
    int kx = hiq ? kxB : kxA;
    const f16* aptr0 = lin + ((wave + ky) * 114 + wi + kx) * 20 + icq;
    bool zq = (j == 4) && hiq;
    const f16* zptr = lB + 152;  // zero pad region of Bt row 0
    f16x8 b0 = *(const f16x8*)(lB + wi * 168 + j * 32 + q * 8);
    f16x8 b1 = *(const f16x8*)(lB + (16 + wi) * 168 + j * 32 + q * 8);
#pragma unroll
    for (int f = 0; f < 7; f++) {
      const f16* ap = zq ? zptr : (aptr0 + f * 320);
      f16x8 a = *(const f16x8*)ap;
      acc[f][0] = __builtin_amdgcn_mfma_f32_16x16x32_f16(a, b0, acc[f][0], 0, 0, 0);
      acc[f][1] = __builtin_amdgcn_mfma_f32_16x16x32_f16(a, b1, acc[f][1], 0, 0, 0);
    }
  }
  // stats
  float s0 = 0.f, q0 = 0.f, s1 = 0.f, q1 = 0.f;
#pragma unroll
  for (int f = 0; f < 7; f++)
#pragma unroll
    for (int r = 0; r < 4; r++) {
      float v0 = acc[f][0][r], v1 = acc[f][1][r];
      s0 += v0; q0 += v0 * v0;
      s1 += v1; q1 += v1 * v1;
    }
  s0 += __shfl_xor(s0, 16, 64); s0 += __shfl_xor(s0, 32, 64);
  q0 += __shfl_xor(q0, 16, 64); q0 += __shfl_xor(q0, 32, 64);
  s1 += __shfl_xor(s1, 16, 64); s1 += __shfl_xor(s1, 32, 64);
  q1 += __shfl_xor(q1, 16, 64); q1 += __shfl_xor(q1, 32, 64);
  if (q == 0) {
    atomicAdd(&lstat[wi], s0);
    atomicAdd(&lstat[16 + wi], s1);
    atomicAdd(&lstat[32 + wi], q0);
    atomicAdd(&lstat[48 + wi], q1);
  }
  // pool: col pairs in-register; row pairs via LDS (waves 1,3 -> 0,2)
  if (wave & 1) {
#pragma unroll
    for (int f = 0; f < 7; f++)
#pragma unroll
      for (int nf = 0; nf < 2; nf++) {
        int ch = nf * 16 + wi;
        int pc0 = f * 8 + q * 2;
        float m0 = fmaxf(acc[f][nf][0], acc[f][nf][1]);
        float m1 = fmaxf(acc[f][nf][2], acc[f][nf][3]);
        lpool[((wave >> 1) * 56 + pc0) * 32 + ch] = (f16)m0;
        lpool[((wave >> 1) * 56 + pc0 + 1) * 32 + ch] = (f16)m1;
      }
  }
  __syncthreads();
  if (!(wave & 1)) {
    int ph = band * 2 + (wave >> 1);
#pragma unroll
    for (int f = 0; f < 7; f++)
#pragma unroll
      for (int nf = 0; nf < 2; nf++) {
        int ch = nf * 16 + wi;
        int pc0 = f * 8 + q * 2;
        float m0 = fmaxf(acc[f][nf][0], acc[f][nf][1]);
        float m1 = fmaxf(acc[f][nf][2], acc[f][nf][3]);
        m0 = fmaxf(m0, (float)lpool[((wave >> 1) * 56 + pc0) * 32 + ch]);
        m1 = fmaxf(m1, (float)lpool[((wave >> 1) * 56 + pc0 + 1) * 32 + ch]);
        size_t ob = (((size_t)n * 56 + ph) * 56) * 32;
        p2[ob + (size_t)pc0 * 32 + ch] = (f16)m0;
        p2[ob + (size_t)(pc0 + 1) * 32 + ch] = (f16)m1;
      }
  }
  if (t < 64) {
    int i = t >> 5, c = t & 31;
    atomicAdd(&banks[(bid & 63) * 64 + i * 32 + c], lstat[i * 32 + c]);
  }
}

// ---------------------------------------------------------------------------
// L3 GEMM (round 7): one block = (n, 4-row band), ALL 64 oc. 3584 blocks.
// lin position stride 36 f16 (bank-spread). Wave: mhalf = wave&1 (112 px),
// nfpair = wave>>1 (32-oc half); 14 f32x4 accs, 126 MFMAs per wave.
// ---------------------------------------------------------------------------
__global__ __launch_bounds__(256) void l3_gemm(const f16* __restrict__ p2,
                                               const f16* __restrict__ Btg,
                                               const float* __restrict__ scsh2,
                                               f16* __restrict__ p3,
                                               float* __restrict__ banks) {
  extern __shared__ char smem[];
  f16* lin = (f16*)smem;                     // [6][58] pos x 36 f16 = 25056 B
  f16* lB = (f16*)(smem + 25056);            // [64][296] = 37888 B
  f16* lpool = (f16*)(smem + 62944);         // [4][28][64] = 14336 B
  float* lstat = (float*)(smem + 77280);     // [2][64] = 512 B
  int bx = blockIdx.x;
  int n = bx / 14, band = bx - n * 14, h0 = band * 4;
  int t = threadIdx.x;
  if (t < 128) lstat[t] = 0.f;
  {
    const uint4* s = (const uint4*)Btg;
    uint4* d = (uint4*)lB;
    for (int i = t; i < 2368; i += 256) d[i] = s[i];
  }
  {
    for (int i = t; i < 1344; i += 256) {
      int r = i / 224, rem = i - r * 224;
      int c = rem >> 2, cp = rem & 3;
      int y = h0 + r - 1;
      f16x8 o = {0, 0, 0, 0, 0, 0, 0, 0};
      if ((unsigned)y < 56u) {
        const f16* src = p2 + (((size_t)(n * 56 + y)) * 56 + c) * 32 + cp * 8;
        f16x8 xv = *(const f16x8*)src;
        int ch0 = cp * 8;
#pragma unroll
        for (int k = 0; k < 8; k++) {
          float f = (float)xv[k] * scsh2[ch0 + k] + scsh2[32 + ch0 + k];
          o[k] = (f16)fmaxf(f, 0.f);
        }
      }
      *(f16x8*)(lin + (r * 58 + 1 + c) * 36 + cp * 8) = o;
    }
    if (t < 48) {
      int r = t / 8, k = t & 7;
      int col = (k < 4) ? 0 : 57, cp = k & 3;
      f16x8 z = {0, 0, 0, 0, 0, 0, 0, 0};
      *(f16x8*)(lin + (r * 58 + col) * 36 + cp * 8) = z;
    }
  }
  __syncthreads();
  int wave = t >> 6, lane = t & 63, q = lane >> 4, wi = lane & 15;
  int mhalf = wave & 1, nfpair = wave >> 1;
  int abase[7];
#pragma unroll
  for (int f = 0; f < 7; f++) {
    int pos = mhalf * 112 + f * 16 + wi;
    int r = pos / 56, w = pos - r * 56;
    abase[f] = (r * 58 + w) * 36 + q * 8;
  }
  f32x4 acc[7][2];
#pragma unroll
  for (int f = 0; f < 7; f++)
#pragma unroll
    for (int nf = 0; nf < 2; nf++)
#pragma unroll
      for (int r = 0; r < 4; r++) acc[f][nf][r] = 0.f;

#pragma unroll
  for (int j = 0; j < 9; j++) {
    const int ky = j / 3, kx = j % 3;
    f16x8 b0 = *(const f16x8*)(lB + (nfpair * 32 + wi) * 296 + j * 32 + q * 8);
    f16x8 b1 =
        *(const f16x8*)(lB + (nfpair * 32 + 16 + wi) * 296 + j * 32 + q * 8);
#pragma unroll
    for (int f = 0; f < 7; f++) {
      f16x8 a = *(const f16x8*)(lin + abase[f] + (ky * 58 + kx) * 36);
      acc[f][0] = __builtin_amdgcn_mfma_f32_16x16x32_f16(a, b0, acc[f][0], 0, 0, 0);
      acc[f][1] = __builtin_amdgcn_mfma_f32_16x16x32_f16(a, b1, acc[f][1], 0, 0, 0);
    }
  }
  int ch0 = nfpair * 32 + wi, ch1 = ch0 + 16;
  // stats
  float s0 = 0.f, q0 = 0.f, s1 = 0.f, q1 = 0.f;
#pragma unroll
  for (int f = 0; f < 7; f++)
#pragma unroll
    for (int r = 0; r < 4; r++) {
      float v0 = acc[f][0][r], v1 = acc[f][1][r];
      s0 += v0; q0 += v0 * v0;
      s1 += v1; q1 += v1 * v1;
    }
  s0 += __shfl_xor(s0, 16, 64); s0 += __shfl_xor(s0, 32, 64);
  q0 += __shfl_xor(q0, 16, 64); q0 += __shfl_xor(q0, 32, 64);
  s1 += __shfl_xor(s1, 16, 64); s1 += __shfl_xor(s1, 32, 64);
  q1 += __shfl_xor(q1, 16, 64); q1 += __shfl_xor(q1, 32, 64);
  if (q == 0) {
    atomicAdd(&lstat[ch0], s0);
    atomicAdd(&lstat[ch1], s1);
    atomicAdd(&lstat[64 + ch0], q0);
    atomicAdd(&lstat[64 + ch1], q1);
  }
  // col-pair maxes -> lpool (D rows m = f*16 + q*4 + r within mhalf)
#pragma unroll
  for (int f = 0; f < 7; f++) {
    int pos = mhalf * 112 + f * 16 + q * 4;  // multiple of 4; w0 <= 52
    int r0 = pos / 56, w0 = pos - r0 * 56;
#pragma unroll
    for (int nf = 0; nf < 2; nf++) {
      int ch = nf ? ch1 : ch0;
      float m0 = fmaxf(acc[f][nf][0], acc[f][nf][1]);
      float m1 = fmaxf(acc[f][nf][2], acc[f][nf][3]);
      lpool[(r0 * 28 + (w0 >> 1)) * 64 + ch] = (f16)m0;
      lpool[(r0 * 28 + (w0 >> 1) + 1) * 64 + ch] = (f16)m1;
    }
  }
  __syncthreads();
  for (int i = t; i < 3584; i += 256) {
    int ch = i & 63, rest = i >> 6;
    int pc = rest % 28, pr = rest / 28;
    float v = fmaxf((float)lpool[((2 * pr) * 28 + pc) * 64 + ch],
                    (float)lpool[((2 * pr + 1) * 28 + pc) * 64 + ch]);
    int gpr = band * 2 + pr;
    p3[(((size_t)n * 28 + gpr) * 28 + pc) * 64 + ch] = (f16)v;
  }
  if (t < 128) {
    atomicAdd(&banks[(bx & 63) * 128 + t], lstat[t]);
  }
}

// ---------------------------------------------------------------------------
// head_pool: BN3+relu+avgpool(p3) coalesced + fc1 -> feat[n][8] (first 5).
// ---------------------------------------------------------------------------
__global__ __launch_bounds__(256) void head_pool(
    const f16* __restrict__ p3, const float* __restrict__ scsh3,
    const float* __restrict__ fc1w, const float* __restrict__ fc1b,
    float* __restrict__ featg) {
  int n = blockIdx.x, t = threadIdx.x;
  __shared__ float red[64 * 33];
  __shared__ float meanc[64];
  int oct = t & 7, strip = t >> 3;
  float sc[8], sh[8];
#pragma unroll
  for (int k = 0; k < 8; k++) {
    sc[k] = scsh3[oct * 8 + k];
    sh[k] = scsh3[64 + oct * 8 + k];
  }
  float acc[8];
#pragma unroll
  for (int k = 0; k < 8; k++) acc[k] = 0.f;
  const f16* base = p3 + (size_t)n * 50176 + oct * 8;
  for (int px = strip; px < 784; px += 32) {
    f16x8 v = *(const f16x8*)(base + (size_t)px * 64);
#pragma unroll
    for (int k = 0; k < 8; k++)
      acc[k] += fmaxf((float)v[k] * sc[k] + sh[k], 0.f);
  }
#pragma unroll
  for (int k = 0; k < 8; k++) red[(oct * 8 + k) * 33 + strip] = acc[k];
  __syncthreads();
  if (t < 64) {
    float s = 0.f;
    for (int j = 0; j < 32; j++) s += red[t * 33 + j];
    meanc[t] = s * (1.f / 784.f);
  }
  __syncthreads();
  if (t < 5) {
    float a = fc1b[t];
    for (int i = 0; i < 64; i++) a += meanc[i] * fc1w[i * 5 + t];
    featg[n * 8 + t] = a;
  }
}

// ---------------------------------------------------------------------------
// Quantum gates in registers. Wire w <-> bit (4-w). (verified rounds 1-6)
// ---------------------------------------------------------------------------
template <int W>
DEV void g_rx(float (&sr)[32], float (&si)[32], float c, float s) {
  constexpr int m = 1 << (4 - W);
#pragma unroll
  for (int i0 = 0; i0 < 32; i0++)
    if (!(i0 & m)) {
      int i1 = i0 | m;
      float a0r = sr[i0], a0i = si[i0], a1r = sr[i1], a1i = si[i1];
      sr[i0] = c * a0r + s * a1i;
      si[i0] = c * a0i - s * a1r;
      sr[i1] = s * a0i + c * a1r;
      si[i1] = -s * a0r + c * a1i;
    }
}

template <int W>
DEV void g_ry(float (&sr)[32], float (&si)[32], float c, float s) {
  constexpr int m = 1 << (4 - W);
#pragma unroll
  for (int i0 = 0; i0 < 32; i0++)
    if (!(i0 & m)) {
      int i1 = i0 | m;
      float a0r = sr[i0], a0i = si[i0], a1r = sr[i1], a1i = si[i1];
      sr[i0] = c * a0r - s * a1r;
      si[i0] = c * a0i - s * a1i;
      sr[i1] = s * a0r + c * a1r;
      si[i1] = s * a0i + c * a1i;
    }
}

template <int W>
DEV void g_rz(float (&sr)[32], float (&si)[32], float c, float s) {
  constexpr int m = 1 << (4 - W);
#pragma unroll
  for (int i0 = 0; i0 < 32; i0++)
    if (!(i0 & m)) {
      int i1 = i0 | m;
      float a0r = sr[i0], a0i = si[i0], a1r = sr[i1], a1i = si[i1];
      sr[i0] = c * a0r + s * a0i;
      si[i0] = c * a0i - s * a0r;
      sr[i1] = c * a1r - s * a1i;
      si[i1] = c * a1i + s * a1r;
    }
}

template <int C, int T>
DEV void g_cnot(float (&sr)[32], float (&si)[32]) {
  constexpr int mc = 1 << (4 - C), mt = 1 << (4 - T);
#pragma unroll
  for (int i0 = 0; i0 < 32; i0++)
    if ((i0 & mc) && !(i0 & mt)) {
      int i1 = i0 | mt;
      float tr = sr[i0]; sr[i0] = sr[i1]; sr[i1] = tr;
      float ti = si[i0]; si[i0] = si[i1]; si[i1] = ti;
    }
}

// ---------------------------------------------------------------------------
// head_q: one thread per sample. LN -> quantum -> fc2 -> relu -> fc3 ->
// log_softmax.
// ---------------------------------------------------------------------------
__global__ __launch_bounds__(64) void head_q(
    const float* __restrict__ featg, const float* __restrict__ lng,
    const float* __restrict__ lnb, const float* __restrict__ qp,
    const float* __restrict__ fc2w, const float* __restrict__ fc2b,
    const float* __restrict__ fc3w, const float* __restrict__ fc3b,
    float* __restrict__ out) {
  int n = blockIdx.x * 64 + threadIdx.x;
  float f[5];
#pragma unroll
  for (int i = 0; i < 5; i++) f[i] = featg[n * 8 + i];
  float mu = (f[0] + f[1] + f[2] + f[3] + f[4]) * 0.2f;
  float var = 0.f;
#pragma unroll
  for (int i = 0; i < 5; i++) { float d = f[i] - mu; var += d * d; }
  var *= 0.2f;
  float inv = rsqrtf(var + 1e-5f);
#pragma unroll
  for (int i = 0; i < 5; i++) f[i] = lng[i] * (f[i] - mu) * inv + lnb[i];

  float cx[5], sx[5];
#pragma unroll
  for (int i = 0; i < 5; i++) {
    cx[i] = cosf(0.5f * f[i]);
    sx[i] = sinf(0.5f * f[i]);
  }
  float sr[32], si[32];
#pragma unroll
  for (int i = 0; i < 32; i++) { sr[i] = 0.f; si[i] = 0.f; }
  sr[0] = 1.f;

  for (int l = 0; l < 3; l++) {
    g_rx<0>(sr, si, cx[0], sx[0]);
    g_rx<1>(sr, si, cx[1], sx[1]);
    g_rx<2>(sr, si, cx[2], sx[2]);
    g_rx<3>(sr, si, cx[3], sx[3]);
    g_rx<4>(sr, si, cx[4], sx[4]);
#define WIRE_YZ(I)                                             \
  {                                                            \
    float ty = qp[l * 10 + I];                                 \
    g_ry<I>(sr, si, cosf(0.5f * ty), sinf(0.5f * ty));         \
    float tz = qp[l * 10 + I + 5];                             \
    g_rz<I>(sr, si, cosf(0.5f * tz), sinf(0.5f * tz));         \
  }
    WIRE_YZ(0) WIRE_YZ(1) WIRE_YZ(2) WIRE_YZ(3) WIRE_YZ(4)
#undef WIRE_YZ
    g_cnot<0, 1>(sr, si);
    g_cnot<1, 2>(sr, si);
    g_cnot<2, 3>(sr, si);
    g_cnot<3, 4>(sr, si);
    g_cnot<4, 0>(sr, si);
  }
  float qv = 0.f;
#pragma unroll
  for (int idx = 0; idx < 32; idx++) {
    float p = sr[idx] * sr[idx] + si[idx] * si[idx];
    qv += (__popc(idx & 0x1C) & 1) ? -p : p;
  }
  float l0 = fc3b[0], l1 = fc3b[1];
  for (int j = 0; j < 32; j++) {
    float hv = fmaxf(qv * fc2w[j] + fc2b[j], 0.f);
    l0 += hv * fc3w[j * 2];
    l1 += hv * fc3w[j * 2 + 1];
  }
  float mx = fmaxf(l0, l1);
  float lse = mx + logf(expf(l0 - mx) + expf(l1 - mx));
  out[n * 2 + 0] = l0 - lse;
  out[n * 2 + 1] = l1 - lse;
}

// ---------------------------------------------------------------------------
extern "C" void kernel_launch(void* const* d_in, const int* in_sizes, int n_in,
                              void* d_out, int out_size, void* d_ws,
                              size_t ws_size, hipStream_t stream) {
  const float* x    = (const float*)d_in[0];
  const float* w1   = (const float*)d_in[1];
  const float* bn1g = (const float*)d_in[3];
  const float* bn1b = (const float*)d_in[4];
  const float* w2   = (const float*)d_in[5];
  const float* bn2g = (const float*)d_in[7];
  const float* bn2b = (const float*)d_in[8];
  const float* w3   = (const float*)d_in[9];
  const float* bn3g = (const float*)d_in[11];
  const float* bn3b = (const float*)d_in[12];
  const float* fc1w = (const float*)d_in[13];
  const float* fc1b = (const float*)d_in[14];
  const float* lng  = (const float*)d_in[15];
  const float* lnb  = (const float*)d_in[16];
  const float* qp   = (const float*)d_in[17];
  const float* fc2w = (const float*)d_in[18];
  const float* fc2b = (const float*)d_in[19];
  const float* fc3w = (const float*)d_in[20];
  const float* fc3b = (const float*)d_in[21];
  float* out = (float*)d_out;

  char* ws = (char*)d_ws;
  float* banks1 = (float*)ws;                 // [64][2][16]  8192 B
  float* banks2 = (float*)(ws + 8192);        // [64][2][32] 16384 B (reused as featg)
  float* banks3 = (float*)(ws + 24576);       // [64][2][64] 32768 B
  float* scsh1 = (float*)(ws + 57344);        // [2][16]
  float* scsh2 = (float*)(ws + 57472);        // [2][32]
  float* scsh3 = (float*)(ws + 57728);        // [2][64]
  f16* Bt2 = (f16*)(ws + 58240);              // 32*168 f16 = 10752 B
  f16* Bt3 = (f16*)(ws + 68992);              // 64*296 f16 = 37888 B
  f16* h1 = (f16*)(ws + 106880);              // 51,380,224 el (raw pooled)
  f16* p2 = (f16*)(ws + 106880 + 102760448ULL);
  f16* p3 = (f16*)(ws + 106880 + 102760448ULL + 51380224ULL);
  float* featg = banks2;                      // free by head time

  hipMemsetAsync(ws, 0, 57344, stream);
  repack<<<16, 256, 0, stream>>>(w2, w3, Bt2, Bt3);
  l1_mfma32<<<3584, 256, 0, stream>>>(x, w1, banks1, h1);
  finalize<<<16, 64, 0, stream>>>(banks1, bn1g, bn1b, scsh1, 16,
                                  1.f / 12845056.f);
  l2_gemm<<<7168, 256, 45536, stream>>>(h1, Bt2, scsh1, p2, banks2);
  finalize<<<32, 64, 0, stream>>>(banks2, bn2g, bn2b, scsh2, 32,
                                  1.f / 3211264.f);
  l3_gemm<<<3584, 256, 77792, stream>>>(p2, Bt3, scsh2, p3, banks3);
  finalize<<<64, 64, 0, stream>>>(banks3, bn3g, bn3b, scsh3, 64,
                                  1.f / 802816.f);
  head_pool<<<256, 256, 0, stream>>>(p3, scsh3, fc1w, fc1b, featg);
  head_q<<<4, 64, 0, stream>>>(featg, lng, lnb, qp, fc2w, fc2b, fc3w, fc3b,
                               out);
}

// Round 8
// 362.345 us; speedup vs baseline: 1.4834x; 1.4834x over previous
//
#include <hip/hip_runtime.h>
#include <hip/hip_bf16.h>

// ============================================================================
// HybridModel round 8: fix round-7 misalignment regression.
//  - Pad strides must be multiples of 8 f16 (16 B) to keep ds_*_b128:
//    l2 lin stride = 24 f16 (48 B, 2-way banks), l3 lin stride = 40 f16
//    (80 B, 2-way banks). Round 7's 20/36 were 8B-aligned -> split b64 loads.
//  - lpool aliases lin (extra barrier) so l3 LDS = 66.2 KB -> 2 blocks/CU.
//  - l3 keeps the zo-merge (one block = all 64 oc). l1/head unchanged.
// ============================================================================

typedef _Float16 f16;
typedef _Float16 f16x2 __attribute__((ext_vector_type(2)));
typedef _Float16 f16x4 __attribute__((ext_vector_type(4)));
typedef _Float16 f16x8 __attribute__((ext_vector_type(8)));
typedef float f32x4 __attribute__((ext_vector_type(4)));
typedef float f32x16 __attribute__((ext_vector_type(16)));

#define DEV static __device__ __forceinline__

DEV float wave_sum(float v) {
#pragma unroll
  for (int off = 32; off > 0; off >>= 1) v += __shfl_xor(v, off, 64);
  return v;
}

// ---------------------------------------------------------------------------
// Weight repack: Bt2[32][168] (k = tap*16+ic, pad 144..167 = 0),
//                Bt3[64][296] (k = tap*32+ic, pad 288..295 = 0), f16.
// ---------------------------------------------------------------------------
__global__ __launch_bounds__(256) void repack(const float* __restrict__ w2,
                                              const float* __restrict__ w3,
                                              f16* __restrict__ Bt2,
                                              f16* __restrict__ Bt3) {
  int t = blockIdx.x * 256 + threadIdx.x;
  int T = gridDim.x * 256;
  for (int i = t; i < 32 * 168; i += T) {
    int oc = i / 168, kk = i - oc * 168;
    float v = 0.f;
    if (kk < 144) {
      int tap = kk >> 4, ic = kk & 15;
      v = w2[(oc * 16 + ic) * 9 + tap];
    }
    Bt2[i] = (f16)v;
  }
  for (int i = t; i < 64 * 296; i += T) {
    int oc = i / 296, kk = i - oc * 296;
    float v = 0.f;
    if (kk < 288) {
      int tap = kk / 32, ic = kk & 31;
      v = w3[(oc * 32 + ic) * 9 + tap];
    }
    Bt3[i] = (f16)v;
  }
}

// ---------------------------------------------------------------------------
// Finalize: banks[64][2][C] -> scsh[2][C]  (scale, shift). 64 thr = 1 wave.
// ---------------------------------------------------------------------------
__global__ __launch_bounds__(64) void finalize(const float* __restrict__ banks,
                                               const float* __restrict__ g,
                                               const float* __restrict__ b,
                                               float* __restrict__ scsh, int C,
                                               float inv_n) {
  int c = blockIdx.x, bk = threadIdx.x;
  float s = banks[bk * 2 * C + c];
  float qq = banks[bk * 2 * C + C + c];
  s = wave_sum(s);
  qq = wave_sum(qq);
  if (bk == 0) {
    float mean = s * inv_n;
    float var = qq * inv_n - mean * mean;
    float sc = g[c] * rsqrtf(var + 1e-5f);
    scsh[c] = sc;
    scsh[C + c] = b[c] - mean * sc;
  }
}

// ---------------------------------------------------------------------------
// L1 via 32x32x16 MFMA (dual-output-row). Unchanged from round 6.
// ---------------------------------------------------------------------------
__global__ __launch_bounds__(256) void l1_mfma32(const float* __restrict__ x,
                                                 const float* __restrict__ w1,
                                                 float* __restrict__ banks,
                                                 f16* __restrict__ h1raw) {
  __shared__ f16 xA[18 * 240];
  __shared__ f16 xB[18 * 240];
  __shared__ f16 lrow[4 * 3616];  // per wave: [2 s][1808]
  __shared__ float lstat[32];
  int bid = blockIdx.x;
  int n = bid / 14, band = bid - n * 14;
  int y0 = band * 16;
  int t = threadIdx.x;
  if (t < 32) lstat[t] = 0.f;
  for (int i = t; i < 1008; i += 256) {
    int r = i / 56, k = i - r * 56;
    int y = y0 - 1 + r;
    float4 v = make_float4(0.f, 0.f, 0.f, 0.f);
    if ((unsigned)y < 224u)
      v = *(const float4*)(x + ((size_t)(n * 224 + y)) * 224 + k * 4);
    f16 h0 = (f16)v.x, h1 = (f16)v.y, h2 = (f16)v.z, h3 = (f16)v.w;
    f16* pa = xA + r * 240 + 4 * k + 1;
    pa[0] = h0; pa[1] = h1; pa[2] = h2; pa[3] = h3;
    f16x4 pk = {h0, h1, h2, h3};
    *(f16x4*)(xB + r * 240 + 4 * k) = pk;
  }
  if (t < 18) {
    xA[t * 240 + 0] = (f16)0.f;
    xA[t * 240 + 225] = (f16)0.f;
    xA[t * 240 + 226] = (f16)0.f;
    xB[t * 240 + 224] = (f16)0.f;
    xB[t * 240 + 225] = (f16)0.f;
  }
  __syncthreads();

  int wave = t >> 6, lane = t & 63;
  int g = lane >> 5, m32 = lane & 31;
  int oc = m32 & 15, s = m32 >> 4;

  f16x8 b;
#pragma unroll
  for (int j = 0; j < 8; j++) {
    int ky = 2 * g + (j >> 2), kx = j & 3;
    int kys = ky - s;
    float wv = 0.f;
    if (kx < 3 && kys >= 0 && kys < 3) wv = w1[oc * 9 + kys * 3 + kx];
    b[j] = (f16)wv;
  }

  const f16* abase = (m32 & 1) ? (xB + (m32 - 1)) : (xA + m32);
  f16* myrow = lrow + wave * 3616;
  f16* mrow = myrow + s * 1808;
  f32x16 zero16;
#pragma unroll
  for (int r = 0; r < 16; r++) zero16[r] = 0.f;
  const int bp[8] = {0, 1, 4, 5, 8, 9, 12, 13};
  float ssum = 0.f, ssq = 0.f;

  for (int rp = wave; rp < 8; rp += 4) {
    int r0 = 2 * rp + 2 * g;
    const f16* rbase = abase + r0 * 240;
#pragma unroll
    for (int xt = 0; xt < 7; xt++) {
      const f16* p0 = rbase + xt * 32;
      f16x2 v0 = *(const f16x2*)(p0);
      f16x2 v1 = *(const f16x2*)(p0 + 2);
      f16x2 v2 = *(const f16x2*)(p0 + 240);
      f16x2 v3 = *(const f16x2*)(p0 + 242);
      f16x8 a = {v0[0], v0[1], v1[0], v1[1], v2[0], v2[1], v3[0], v3[1]};
      f32x16 acc = __builtin_amdgcn_mfma_f32_32x32x16_f16(a, b, zero16, 0, 0, 0);
#pragma unroll
      for (int r = 0; r < 16; r++) {
        float v = acc[r];
        ssum += v;
        ssq += v * v;
      }
#pragma unroll
      for (int i = 0; i < 8; i++) {
        float pm = fmaxf(acc[2 * i], acc[2 * i + 1]);
        int pxp = xt * 16 + bp[i] + 2 * g;
        mrow[pxp * 16 + oc] = (f16)pm;
      }
    }
    int ph = band * 8 + rp;
    f16* gdst = h1raw + ((size_t)(n * 112) + ph) * 112 * 16;
    for (int i = lane; i < 224; i += 64) {
      f16x8 va = *(const f16x8*)(myrow + i * 8);
      f16x8 vb = *(const f16x8*)(myrow + 1808 + i * 8);
#pragma unroll
      for (int k = 0; k < 8; k++) va[k] = (va[k] > vb[k]) ? va[k] : vb[k];
      *(f16x8*)(gdst + i * 8) = va;
    }
  }
  ssum += __shfl_xor(ssum, 16, 64);
  ssum += __shfl_xor(ssum, 32, 64);
  ssq += __shfl_xor(ssq, 16, 64);
  ssq += __shfl_xor(ssq, 32, 64);
  if (lane < 16) {
    atomicAdd(&lstat[oc], ssum);
    atomicAdd(&lstat[16 + oc], ssq);
  }
  __syncthreads();
  if (t < 32) atomicAdd(&banks[(bid & 63) * 32 + t], lstat[t]);
}

// ---------------------------------------------------------------------------
// L2 GEMM: h1raw -> stage BN1+relu -> raw conv2, stats + maxpool -> p2.
// Round 8: lin position stride 24 f16 (48 B: 16B-aligned, 2-way banks max).
// lpool aliases lin (barrier after MFMA loop). LDS total 43840 B.
// ---------------------------------------------------------------------------
__global__ __launch_bounds__(256) void l2_gemm(const f16* __restrict__ h1,
                                               const f16* __restrict__ Btg,
                                               const float* __restrict__ scsh1,
                                               f16* __restrict__ p2,
                                               float* __restrict__ banks) {
  extern __shared__ char smem[];
  f16* lin = (f16*)smem;                    // [6][114] pos x 24 f16 = 32832 B
  f16* lB = (f16*)(smem + 32832);           // [32][168] = 10752 B
  float* lstat = (float*)(smem + 43584);    // [2][32]   =   256 B
  f16* lpool = (f16*)smem;                  // aliases lin post-barrier (7168 B)
  int bid = blockIdx.x;
  int n = bid / 28, band = bid - n * 28, h0 = band * 4;
  int t = threadIdx.x;
  if (t < 64) lstat[t] = 0.f;
  {
    const uint4* s = (const uint4*)Btg;
    uint4* d = (uint4*)lB;
    for (int i = t; i < 672; i += 256) d[i] = s[i];
  }
  {
    for (int i = t; i < 1344; i += 256) {
      int r = i / 224, c = i - r * 224;  // c: f16x8 unit (pos = c>>1, half = c&1)
      int y = h0 + r - 1;
      f16x8 o = {0, 0, 0, 0, 0, 0, 0, 0};
      if ((unsigned)y < 112u) {
        f16x8 xv =
            *(const f16x8*)(h1 + ((size_t)(n * 112 + y)) * 112 * 16 + c * 8);
        int ch0 = (c & 1) * 8;
#pragma unroll
        for (int k = 0; k < 8; k++) {
          float f = (float)xv[k] * scsh1[ch0 + k] + scsh1[16 + ch0 + k];
          o[k] = (f16)fmaxf(f, 0.f);
        }
      }
      *(f16x8*)(lin + (r * 114 + 1 + (c >> 1)) * 24 + (c & 1) * 8) = o;
    }
    if (t < 24) {
      int r = t >> 2, k = t & 3;
      f16x8 z = {0, 0, 0, 0, 0, 0, 0, 0};
      int pos = (k < 2) ? 0 : 113;
      *(f16x8*)(lin + (r * 114 + pos) * 24 + (k & 1) * 8) = z;
    }
  }
  __syncthreads();
  int wave = t >> 6, lane = t & 63, q = lane >> 4, wi = lane & 15;
  const int icq = (q & 1) * 8;
  f32x4 acc[7][2];
#pragma unroll
  for (int f = 0; f < 7; f++)
#pragma unroll
    for (int nf = 0; nf < 2; nf++)
#pragma unroll
      for (int r = 0; r < 4; r++) acc[f][nf][r] = 0.f;

#pragma unroll
  for (int j = 0; j < 5; j++) {
    const int tA = 2 * j, tB = 2 * j + 1;
    const int kyA = tA / 3, kxA = tA % 3;
    const int kyB = (tB < 9) ? tB / 3 : 0, kxB = (tB < 9) ? tB % 3 : 0;
    bool hiq = (q >= 2);
    int ky = hiq ? kyB : kyA;
    int kx = hiq ? kxB : kxA;
    const f16* aptr0 = lin + ((wave + ky) * 114 + wi + kx) * 24 + icq;
    bool zq = (j == 4) && hiq;
    const f16* zptr = lB + 152;  // zero pad region of Bt row 0 (16B-aligned)
    f16x8 b0 = *(const f16x8*)(lB + wi * 168 + j * 32 + q * 8);
    f16x8 b1 = *(const f16x8*)(lB + (16 + wi) * 168 + j * 32 + q * 8);
#pragma unroll
    for (int f = 0; f < 7; f++) {
      const f16* ap = zq ? zptr : (aptr0 + f * 384);
      f16x8 a = *(const f16x8*)ap;
      acc[f][0] = __builtin_amdgcn_mfma_f32_16x16x32_f16(a, b0, acc[f][0], 0, 0, 0);
      acc[f][1] = __builtin_amdgcn_mfma_f32_16x16x32_f16(a, b1, acc[f][1], 0, 0, 0);
    }
  }
  // stats (raw conv, pre-pool): D layout m = q*4+reg, n-ch = wi
  float s0 = 0.f, q0 = 0.f, s1 = 0.f, q1 = 0.f;
#pragma unroll
  for (int f = 0; f < 7; f++)
#pragma unroll
    for (int r = 0; r < 4; r++) {
      float v0 = acc[f][0][r], v1 = acc[f][1][r];
      s0 += v0; q0 += v0 * v0;
      s1 += v1; q1 += v1 * v1;
    }
  s0 += __shfl_xor(s0, 16, 64); s0 += __shfl_xor(s0, 32, 64);
  q0 += __shfl_xor(q0, 16, 64); q0 += __shfl_xor(q0, 32, 64);
  s1 += __shfl_xor(s1, 16, 64); s1 += __shfl_xor(s1, 32, 64);
  q1 += __shfl_xor(q1, 16, 64); q1 += __shfl_xor(q1, 32, 64);
  if (q == 0) {
    atomicAdd(&lstat[wi], s0);
    atomicAdd(&lstat[16 + wi], s1);
    atomicAdd(&lstat[32 + wi], q0);
    atomicAdd(&lstat[48 + wi], q1);
  }
  __syncthreads();  // all lin reads done; lpool may now alias lin
  // pool: col pairs in-register; row pairs via LDS (waves 1,3 -> 0,2)
  if (wave & 1) {
#pragma unroll
    for (int f = 0; f < 7; f++)
#pragma unroll
      for (int nf = 0; nf < 2; nf++) {
        int ch = nf * 16 + wi;
        int pc0 = f * 8 + q * 2;
        float m0 = fmaxf(acc[f][nf][0], acc[f][nf][1]);
        float m1 = fmaxf(acc[f][nf][2], acc[f][nf][3]);
        lpool[((wave >> 1) * 56 + pc0) * 32 + ch] = (f16)m0;
        lpool[((wave >> 1) * 56 + pc0 + 1) * 32 + ch] = (f16)m1;
      }
  }
  __syncthreads();
  if (!(wave & 1)) {
    int ph = band * 2 + (wave >> 1);
#pragma unroll
    for (int f = 0; f < 7; f++)
#pragma unroll
      for (int nf = 0; nf < 2; nf++) {
        int ch = nf * 16 + wi;
        int pc0 = f * 8 + q * 2;
        float m0 = fmaxf(acc[f][nf][0], acc[f][nf][1]);
        float m1 = fmaxf(acc[f][nf][2], acc[f][nf][3]);
        m0 = fmaxf(m0, (float)lpool[((wave >> 1) * 56 + pc0) * 32 + ch]);
        m1 = fmaxf(m1, (float)lpool[((wave >> 1) * 56 + pc0 + 1) * 32 + ch]);
        size_t ob = (((size_t)n * 56 + ph) * 56) * 32;
        p2[ob + (size_t)pc0 * 32 + ch] = (f16)m0;
        p2[ob + (size_t)(pc0 + 1) * 32 + ch] = (f16)m1;
      }
  }
  if (t < 64) {
    int i = t >> 5, c = t & 31;
    atomicAdd(&banks[(bid & 63) * 64 + i * 32 + c], lstat[i * 32 + c]);
  }
}

// ---------------------------------------------------------------------------
// L3 GEMM: one block = (n, 4-row band), all 64 oc. lin stride 40 f16 (80 B:
// aligned, 2-way banks). lpool aliases lin. LDS total 66240 B (2 blocks/CU).
// ---------------------------------------------------------------------------
__global__ __launch_bounds__(256) void l3_gemm(const f16* __restrict__ p2,
                                               const f16* __restrict__ Btg,
                                               const float* __restrict__ scsh2,
                                               f16* __restrict__ p3,
                                               float* __restrict__ banks) {
  extern __shared__ char smem[];
  f16* lin = (f16*)smem;                     // [6][58] pos x 40 f16 = 27840 B
  f16* lB = (f16*)(smem + 27840);            // [64][296] = 37888 B
  float* lstat = (float*)(smem + 65728);     // [2][64] = 512 B
  f16* lpool = (f16*)smem;                   // aliases lin post-barrier (14336 B)
  int bx = blockIdx.x;
  int n = bx / 14, band = bx - n * 14, h0 = band * 4;
  int t = threadIdx.x;
  if (t < 128) lstat[t] = 0.f;
  {
    const uint4* s = (const uint4*)Btg;
    uint4* d = (uint4*)lB;
    for (int i = t; i < 2368; i += 256) d[i] = s[i];
  }
  {
    for (int i = t; i < 1344; i += 256) {
      int r = i / 224, rem = i - r * 224;
      int c = rem >> 2, cp = rem & 3;
      int y = h0 + r - 1;
      f16x8 o = {0, 0, 0, 0, 0, 0, 0, 0};
      if ((unsigned)y < 56u) {
        const f16* src = p2 + (((size_t)(n * 56 + y)) * 56 + c) * 32 + cp * 8;
        f16x8 xv = *(const f16x8*)src;
        int ch0 = cp * 8;
#pragma unroll
        for (int k = 0; k < 8; k++) {
          float f = (float)xv[k] * scsh2[ch0 + k] + scsh2[32 + ch0 + k];
          o[k] = (f16)fmaxf(f, 0.f);
        }
      }
      *(f16x8*)(lin + (r * 58 + 1 + c) * 40 + cp * 8) = o;
    }
    if (t < 48) {
      int r = t / 8, k = t & 7;
      int col = (k < 4) ? 0 : 57, cp = k & 3;
      f16x8 z = {0, 0, 0, 0, 0, 0, 0, 0};
      *(f16x8*)(lin + (r * 58 + col) * 40 + cp * 8) = z;
    }
  }
  __syncthreads();
  int wave = t >> 6, lane = t & 63, q = lane >> 4, wi = lane & 15;
  int mhalf = wave & 1, nfpair = wave >> 1;
  int abase[7];
#pragma unroll
  for (int f = 0; f < 7; f++) {
    int pos = mhalf * 112 + f * 16 + wi;
    int r = pos / 56, w = pos - r * 56;
    abase[f] = (r * 58 + w) * 40 + q * 8;
  }
  f32x4 acc[7][2];
#pragma unroll
  for (int f = 0; f < 7; f++)
#pragma unroll
    for (int nf = 0; nf < 2; nf++)
#pragma unroll
      for (int r = 0; r < 4; r++) acc[f][nf][r] = 0.f;

#pragma unroll
  for (int j = 0; j < 9; j++) {
    const int ky = j / 3, kx = j % 3;
    f16x8 b0 = *(const f16x8*)(lB + (nfpair * 32 + wi) * 296 + j * 32 + q * 8);
    f16x8 b1 =
        *(const f16x8*)(lB + (nfpair * 32 + 16 + wi) * 296 + j * 32 + q * 8);
#pragma unroll
    for (int f = 0; f < 7; f++) {
      f16x8 a = *(const f16x8*)(lin + abase[f] + (ky * 58 + kx) * 40);
      acc[f][0] = __builtin_amdgcn_mfma_f32_16x16x32_f16(a, b0, acc[f][0], 0, 0, 0);
      acc[f][1] = __builtin_amdgcn_mfma_f32_16x16x32_f16(a, b1, acc[f][1], 0, 0, 0);
    }
  }
  int ch0 = nfpair * 32 + wi, ch1 = ch0 + 16;
  // stats
  float s0 = 0.f, q0 = 0.f, s1 = 0.f, q1 = 0.f;
#pragma unroll
  for (int f = 0; f < 7; f++)
#pragma unroll
    for (int r = 0; r < 4; r++) {
      float v0 = acc[f][0][r], v1 = acc[f][1][r];
      s0 += v0; q0 += v0 * v0;
      s1 += v1; q1 += v1 * v1;
    }
  s0 += __shfl_xor(s0, 16, 64); s0 += __shfl_xor(s0, 32, 64);
  q0 += __shfl_xor(q0, 16, 64); q0 += __shfl_xor(q0, 32, 64);
  s1 += __shfl_xor(s1, 16, 64); s1 += __shfl_xor(s1, 32, 64);
  q1 += __shfl_xor(q1, 16, 64); q1 += __shfl_xor(q1, 32, 64);
  if (q == 0) {
    atomicAdd(&lstat[ch0], s0);
    atomicAdd(&lstat[ch1], s1);
    atomicAdd(&lstat[64 + ch0], q0);
    atomicAdd(&lstat[64 + ch1], q1);
  }
  __syncthreads();  // all lin reads done; lpool may now alias lin
  // col-pair maxes -> lpool (D rows m = f*16 + q*4 + r within mhalf)
#pragma unroll
  for (int f = 0; f < 7; f++) {
    int pos = mhalf * 112 + f * 16 + q * 4;  // multiple of 4; w0 <= 52
    int r0 = pos / 56, w0 = pos - r0 * 56;
#pragma unroll
    for (int nf = 0; nf < 2; nf++) {
      int ch = nf ? ch1 : ch0;
      float m0 = fmaxf(acc[f][nf][0], acc[f][nf][1]);
      float m1 = fmaxf(acc[f][nf][2], acc[f][nf][3]);
      lpool[(r0 * 28 + (w0 >> 1)) * 64 + ch] = (f16)m0;
      lpool[(r0 * 28 + (w0 >> 1) + 1) * 64 + ch] = (f16)m1;
    }
  }
  __syncthreads();
  for (int i = t; i < 3584; i += 256) {
    int ch = i & 63, rest = i >> 6;
    int pc = rest % 28, pr = rest / 28;
    float v = fmaxf((float)lpool[((2 * pr) * 28 + pc) * 64 + ch],
                    (float)lpool[((2 * pr + 1) * 28 + pc) * 64 + ch]);
    int gpr = band * 2 + pr;
    p3[(((size_t)n * 28 + gpr) * 28 + pc) * 64 + ch] = (f16)v;
  }
  if (t < 128) {
    atomicAdd(&banks[(bx & 63) * 128 + t], lstat[t]);
  }
}

// ---------------------------------------------------------------------------
// head_pool: BN3+relu+avgpool(p3) coalesced + fc1 -> feat[n][8] (first 5).
// ---------------------------------------------------------------------------
__global__ __launch_bounds__(256) void head_pool(
    const f16* __restrict__ p3, const float* __restrict__ scsh3,
    const float* __restrict__ fc1w, const float* __restrict__ fc1b,
    float* __restrict__ featg) {
  int n = blockIdx.x, t = threadIdx.x;
  __shared__ float red[64 * 33];
  __shared__ float meanc[64];
  int oct = t & 7, strip = t >> 3;
  float sc[8], sh[8];
#pragma unroll
  for (int k = 0; k < 8; k++) {
    sc[k] = scsh3[oct * 8 + k];
    sh[k] = scsh3[64 + oct * 8 + k];
  }
  float acc[8];
#pragma unroll
  for (int k = 0; k < 8; k++) acc[k] = 0.f;
  const f16* base = p3 + (size_t)n * 50176 + oct * 8;
  for (int px = strip; px < 784; px += 32) {
    f16x8 v = *(const f16x8*)(base + (size_t)px * 64);
#pragma unroll
    for (int k = 0; k < 8; k++)
      acc[k] += fmaxf((float)v[k] * sc[k] + sh[k], 0.f);
  }
#pragma unroll
  for (int k = 0; k < 8; k++) red[(oct * 8 + k) * 33 + strip] = acc[k];
  __syncthreads();
  if (t < 64) {
    float s = 0.f;
    for (int j = 0; j < 32; j++) s += red[t * 33 + j];
    meanc[t] = s * (1.f / 784.f);
  }
  __syncthreads();
  if (t < 5) {
    float a = fc1b[t];
    for (int i = 0; i < 64; i++) a += meanc[i] * fc1w[i * 5 + t];
    featg[n * 8 + t] = a;
  }
}

// ---------------------------------------------------------------------------
// Quantum gates in registers. Wire w <-> bit (4-w). (verified rounds 1-7)
// ---------------------------------------------------------------------------
template <int W>
DEV void g_rx(float (&sr)[32], float (&si)[32], float c, float s) {
  constexpr int m = 1 << (4 - W);
#pragma unroll
  for (int i0 = 0; i0 < 32; i0++)
    if (!(i0 & m)) {
      int i1 = i0 | m;
      float a0r = sr[i0], a0i = si[i0], a1r = sr[i1], a1i = si[i1];
      sr[i0] = c * a0r + s * a1i;
      si[i0] = c * a0i - s * a1r;
      sr[i1] = s * a0i + c * a1r;
      si[i1] = -s * a0r + c * a1i;
    }
}

template <int W>
DEV void g_ry(float (&sr)[32], float (&si)[32], float c, float s) {
  constexpr int m = 1 << (4 - W);
#pragma unroll
  for (int i0 = 0; i0 < 32; i0++)
    if (!(i0 & m)) {
      int i1 = i0 | m;
      float a0r = sr[i0], a0i = si[i0], a1r = sr[i1], a1i = si[i1];
      sr[i0] = c * a0r - s * a1r;
      si[i0] = c * a0i - s * a1i;
      sr[i1] = s * a0r + c * a1r;
      si[i1] = s * a0i + c * a1i;
    }
}

template <int W>
DEV void g_rz(float (&sr)[32], float (&si)[32], float c, float s) {
  constexpr int m = 1 << (4 - W);
#pragma unroll
  for (int i0 = 0; i0 < 32; i0++)
    if (!(i0 & m)) {
      int i1 = i0 | m;
      float a0r = sr[i0], a0i = si[i0], a1r = sr[i1], a1i = si[i1];
      sr[i0] = c * a0r + s * a0i;
      si[i0] = c * a0i - s * a0r;
      sr[i1] = c * a1r - s * a1i;
      si[i1] = c * a1i + s * a1r;
    }
}

template <int C, int T>
DEV void g_cnot(float (&sr)[32], float (&si)[32]) {
  constexpr int mc = 1 << (4 - C), mt = 1 << (4 - T);
#pragma unroll
  for (int i0 = 0; i0 < 32; i0++)
    if ((i0 & mc) && !(i0 & mt)) {
      int i1 = i0 | mt;
      float tr = sr[i0]; sr[i0] = sr[i1]; sr[i1] = tr;
      float ti = si[i0]; si[i0] = si[i1]; si[i1] = ti;
    }
}

// ---------------------------------------------------------------------------
// head_q: one thread per sample. LN -> quantum -> fc2 -> relu -> fc3 ->
// log_softmax.
// ---------------------------------------------------------------------------
__global__ __launch_bounds__(64) void head_q(
    const float* __restrict__ featg, const float* __restrict__ lng,
    const float* __restrict__ lnb, const float* __restrict__ qp,
    const float* __restrict__ fc2w, const float* __restrict__ fc2b,
    const float* __restrict__ fc3w, const float* __restrict__ fc3b,
    float* __restrict__ out) {
  int n = blockIdx.x * 64 + threadIdx.x;
  float f[5];
#pragma unroll
  for (int i = 0; i < 5; i++) f[i] = featg[n * 8 + i];
  float mu = (f[0] + f[1] + f[2] + f[3] + f[4]) * 0.2f;
  float var = 0.f;
#pragma unroll
  for (int i = 0; i < 5; i++) { float d = f[i] - mu; var += d * d; }
  var *= 0.2f;
  float inv = rsqrtf(var + 1e-5f);
#pragma unroll
  for (int i = 0; i < 5; i++) f[i] = lng[i] * (f[i] - mu) * inv + lnb[i];

  float cx[5], sx[5];
#pragma unroll
  for (int i = 0; i < 5; i++) {
    cx[i] = cosf(0.5f * f[i]);
    sx[i] = sinf(0.5f * f[i]);
  }
  float sr[32], si[32];
#pragma unroll
  for (int i = 0; i < 32; i++) { sr[i] = 0.f; si[i] = 0.f; }
  sr[0] = 1.f;

  for (int l = 0; l < 3; l++) {
    g_rx<0>(sr, si, cx[0], sx[0]);
    g_rx<1>(sr, si, cx[1], sx[1]);
    g_rx<2>(sr, si, cx[2], sx[2]);
    g_rx<3>(sr, si, cx[3], sx[3]);
    g_rx<4>(sr, si, cx[4], sx[4]);
#define WIRE_YZ(I)                                             \
  {                                                            \
    float ty = qp[l * 10 + I];                                 \
    g_ry<I>(sr, si, cosf(0.5f * ty), sinf(0.5f * ty));         \
    float tz = qp[l * 10 + I + 5];                             \
    g_rz<I>(sr, si, cosf(0.5f * tz), sinf(0.5f * tz));         \
  }
    WIRE_YZ(0) WIRE_YZ(1) WIRE_YZ(2) WIRE_YZ(3) WIRE_YZ(4)
#undef WIRE_YZ
    g_cnot<0, 1>(sr, si);
    g_cnot<1, 2>(sr, si);
    g_cnot<2, 3>(sr, si);
    g_cnot<3, 4>(sr, si);
    g_cnot<4, 0>(sr, si);
  }
  float qv = 0.f;
#pragma unroll
  for (int idx = 0; idx < 32; idx++) {
    float p = sr[idx] * sr[idx] + si[idx] * si[idx];
    qv += (__popc(idx & 0x1C) & 1) ? -p : p;
  }
  float l0 = fc3b[0], l1 = fc3b[1];
  for (int j = 0; j < 32; j++) {
    float hv = fmaxf(qv * fc2w[j] + fc2b[j], 0.f);
    l0 += hv * fc3w[j * 2];
    l1 += hv * fc3w[j * 2 + 1];
  }
  float mx = fmaxf(l0, l1);
  float lse = mx + logf(expf(l0 - mx) + expf(l1 - mx));
  out[n * 2 + 0] = l0 - lse;
  out[n * 2 + 1] = l1 - lse;
}

// ---------------------------------------------------------------------------
extern "C" void kernel_launch(void* const* d_in, const int* in_sizes, int n_in,
                              void* d_out, int out_size, void* d_ws,
                              size_t ws_size, hipStream_t stream) {
  const float* x    = (const float*)d_in[0];
  const float* w1   = (const float*)d_in[1];
  const float* bn1g = (const float*)d_in[3];
  const float* bn1b = (const float*)d_in[4];
  const float* w2   = (const float*)d_in[5];
  const float* bn2g = (const float*)d_in[7];
  const float* bn2b = (const float*)d_in[8];
  const float* w3   = (const float*)d_in[9];
  const float* bn3g = (const float*)d_in[11];
  const float* bn3b = (const float*)d_in[12];
  const float* fc1w = (const float*)d_in[13];
  const float* fc1b = (const float*)d_in[14];
  const float* lng  = (const float*)d_in[15];
  const float* lnb  = (const float*)d_in[16];
  const float* qp   = (const float*)d_in[17];
  const float* fc2w = (const float*)d_in[18];
  const float* fc2b = (const float*)d_in[19];
  const float* fc3w = (const float*)d_in[20];
  const float* fc3b = (const float*)d_in[21];
  float* out = (float*)d_out;

  char* ws = (char*)d_ws;
  float* banks1 = (float*)ws;                 // [64][2][16]  8192 B
  float* banks2 = (float*)(ws + 8192);        // [64][2][32] 16384 B (reused as featg)
  float* banks3 = (float*)(ws + 24576);       // [64][2][64] 32768 B
  float* scsh1 = (float*)(ws + 57344);        // [2][16]
  float* scsh2 = (float*)(ws + 57472);        // [2][32]
  float* scsh3 = (float*)(ws + 57728);        // [2][64]
  f16* Bt2 = (f16*)(ws + 58240);              // 32*168 f16 = 10752 B
  f16* Bt3 = (f16*)(ws + 68992);              // 64*296 f16 = 37888 B
  f16* h1 = (f16*)(ws + 106880);              // 51,380,224 el (raw pooled)
  f16* p2 = (f16*)(ws + 106880 + 102760448ULL);
  f16* p3 = (f16*)(ws + 106880 + 102760448ULL + 51380224ULL);
  float* featg = banks2;                      // free by head time

  hipMemsetAsync(ws, 0, 57344, stream);
  repack<<<16, 256, 0, stream>>>(w2, w3, Bt2, Bt3);
  l1_mfma32<<<3584, 256, 0, stream>>>(x, w1, banks1, h1);
  finalize<<<16, 64, 0, stream>>>(banks1, bn1g, bn1b, scsh1, 16,
                                  1.f / 12845056.f);
  l2_gemm<<<7168, 256, 43840, stream>>>(h1, Bt2, scsh1, p2, banks2);
  finalize<<<32, 64, 0, stream>>>(banks2, bn2g, bn2b, scsh2, 32,
                                  1.f / 3211264.f);
  l3_gemm<<<3584, 256, 66240, stream>>>(p2, Bt3, scsh2, p3, banks3);
  finalize<<<64, 64, 0, stream>>>(banks3, bn3g, bn3b, scsh3, 64,
                                  1.f / 802816.f);
  head_pool<<<256, 256, 0, stream>>>(p3, scsh3, fc1w, fc1b, featg);
  head_q<<<4, 64, 0, stream>>>(featg, lng, lnb, qp, fc2w, fc2b, fc3w, fc3b,
                               out);
}